// Round 9
// baseline (551.821 us; speedup 1.0000x reference)
//
#include <hip/hip_runtime.h>
#include <hip/hip_fp16.h>
#include <hip/hip_cooperative_groups.h>

namespace cg = cooperative_groups;

#define DD 300
#define SS 512
#define VV 50000
#define NF4 75

// Workspace layout (float index):
#define CK       0
#define CQ       1
#define CQS      2
#define U_OFF    16       // u  = wk@Wk (300)
#define UQ_OFF   320      // uq = wq@Wq (300)
#define UQWX_OFF 640      // uqWx = Wx^T@uq (300)
#define BC_OFF   960      // bc = Wp@bk+bp (300)
#define WXT_OFF  2048     // WxT[e*300+i] = Wx[i,e] (90000)
#define WCT_OFF  92160    // WcT[e*300+i] = (Wp@Wk)[i,e] (90000)
#define QS_OFF   182272   // qs[b] (512)
#define X0_OFF   182784   // X0[b*304+i]
#define XN_OFF   338432   // XN[b*304+i]
#define MV_OFF   494080   // mv[b*304+i]
#define S0_OFF   649728   // s0[b] (512 ints)
#define KS_OFF   650240   // ks[b*512+s] (262144)
#define EU_OFF   912384   // eu[v] (50000)
#define E16_OFF  962560   // fp16 emb copy (600 B/row)

#define FMA4(acc, s, v) { acc.x += (s)*(v).x; acc.y += (s)*(v).y; \
                          acc.z += (s)*(v).z; acc.w += (s)*(v).w; }

__device__ __forceinline__ float fast_exp_tanh(float z) {
    const float t = __expf(2.0f * z);
    return __expf(1.0f - 2.0f / (t + 1.0f));
}

union __align__(16) CoopU {
    struct { int ti[SS]; float cw[SS]; float red[16]; float mpart[16][304]; } a;
    struct { float As[2][304]; float part[3][2][304]; float red[16]; } g;
    struct { float uq_s[304]; float p0[3][304]; float red0[16]; } p;
    struct { float u_s[304]; } t;
    struct { float red[16]; } c;
};

// ---------------------------------------------------------------------------
// pre: 202 blocks x 1024. 0..99: WcT rows (transposed store); 100..199:
// Wx->WxT transpose tiles; 200: u,c_k; 201: uq,c_q,bc.  (validated in R7)
// ---------------------------------------------------------------------------
__global__ __launch_bounds__(1024) void pre(
    const float* __restrict__ Wk, const float* __restrict__ bk,
    const float* __restrict__ Wq, const float* __restrict__ bq,
    const float* __restrict__ w_mlp,
    const float* __restrict__ Wp, const float* __restrict__ bp,
    const float* __restrict__ Wx,
    float* __restrict__ ws)
{
    const int blk  = blockIdx.x;
    const int tid  = threadIdx.x;
    const int wv   = tid >> 6;
    const int lane = tid & 63;
    __shared__ __align__(16) float buf[16 * 304 * 3 + 3 * 304];
    __shared__ float red[16];

    if (blk < 100) {
        const int i0 = blk * 3;
        float* sWp = buf + 16 * 304 * 3;
        for (int r = tid; r < 3 * DD; r += 1024)
            sWp[(r / DD) * 304 + (r % DD)] = Wp[i0 * DD + r];
        __syncthreads();

        float4 a00{0,0,0,0}, a01{0,0,0,0}, a10{0,0,0,0},
               a11{0,0,0,0}, a20{0,0,0,0}, a21{0,0,0,0};
        for (int e = wv; e < DD; e += 16) {
            const float4* kr = (const float4*)(Wk + e * DD);
            const float4 k0 = kr[lane];
            const float p0 = sWp[e], p1 = sWp[304 + e], p2 = sWp[608 + e];
            FMA4(a00, p0, k0); FMA4(a10, p1, k0); FMA4(a20, p2, k0);
            if (lane < 11) {
                const float4 k1 = kr[64 + lane];
                FMA4(a01, p0, k1); FMA4(a11, p1, k1); FMA4(a21, p2, k1);
            }
        }
        float4* p0r = (float4*)(buf + (wv * 3 + 0) * 304);
        float4* p1r = (float4*)(buf + (wv * 3 + 1) * 304);
        float4* p2r = (float4*)(buf + (wv * 3 + 2) * 304);
        p0r[lane] = a00; p1r[lane] = a10; p2r[lane] = a20;
        if (lane < 11) { p0r[64+lane] = a01; p1r[64+lane] = a11; p2r[64+lane] = a21; }
        __syncthreads();
        if (tid < DD) {
            #pragma unroll
            for (int r = 0; r < 3; ++r) {
                float s = 0.f;
                for (int w = 0; w < 16; ++w) s += buf[(w * 3 + r) * 304 + tid];
                ws[WCT_OFF + tid * DD + i0 + r] = s;
            }
        }
        return;
    }

    if (blk < 200) {
        const int tb = blk - 100;
        const int bi = tb / 10, bj = tb % 10;
        __shared__ __align__(16) float tile[32][33];
        const int ty = tid >> 5, tx = tid & 31;
        {
            const int r = bi * 32 + ty, c = bj * 32 + tx;
            if (r < DD && c < DD) tile[ty][tx] = Wx[r * DD + c];
        }
        __syncthreads();
        {
            const int ro = bj * 32 + ty, co = bi * 32 + tx;
            if (ro < DD && co < DD) ws[WXT_OFF + ro * DD + co] = tile[tx][ty];
        }
        return;
    }

    const float* M  = (blk == 200) ? Wk : Wq;
    const float* vw = (blk == 200) ? w_mlp : (w_mlp + DD);
    float* s_w = buf + 16 * 304;
    float* s_b = buf + 16 * 304 + 304;
    if (tid < DD) {
        s_w[tid] = vw[tid];
        if (blk == 201) s_b[tid] = bk[tid];
    }
    __syncthreads();

    float4 a0{0,0,0,0}, a1{0,0,0,0};
    for (int e = wv; e < DD; e += 16) {
        const float4* kr = (const float4*)(M + e * DD);
        const float s = s_w[e];
        FMA4(a0, s, kr[lane]);
        if (lane < 11) { const float4 k1 = kr[64 + lane]; FMA4(a1, s, k1); }
    }
    float4* pr = (float4*)(buf + wv * 304);
    pr[lane] = a0;
    if (lane < 11) pr[64 + lane] = a1;

    float pk = 0.f;
    if (tid < DD) pk = ((blk == 200) ? bk[tid] : bq[tid]) * s_w[tid];
    #pragma unroll
    for (int off = 32; off; off >>= 1) pk += __shfl_xor(pk, off);
    if (lane == 0) red[wv] = pk;
    __syncthreads();

    const int voff = (blk == 200) ? U_OFF : UQ_OFF;
    if (tid < DD) {
        float s = 0.f;
        #pragma unroll
        for (int w = 0; w < 16; ++w) s += buf[w * 304 + tid];
        ws[voff + tid] = s;
    }
    if (tid == 0) {
        float s = 0.f;
        for (int w = 0; w < 16; ++w) s += red[w];
        ws[(blk == 200) ? CK : CQ] = s;
    }
    if (blk == 201) {
        const float4* b4 = (const float4*)s_b;
        const float4 k0 = b4[lane];
        const float4 k1 = (lane < 11) ? b4[64 + lane] : float4{0, 0, 0, 0};
        for (int i2 = wv; i2 < DD; i2 += 16) {
            const float4* wr = (const float4*)(Wp + i2 * DD);
            const float4 w0 = wr[lane];
            float a = w0.x * k0.x + w0.y * k0.y + w0.z * k0.z + w0.w * k0.w;
            if (lane < 11) {
                const float4 w1 = wr[64 + lane];
                a += w1.x * k1.x + w1.y * k1.y + w1.z * k1.z + w1.w * k1.w;
            }
            #pragma unroll
            for (int off = 32; off; off >>= 1) a += __shfl_xor(a, off);
            if (lane == 0) ws[BC_OFF + i2] = a + bp[i2];
        }
    }
}

// ---------------------------------------------------------------------------
// Phase device functions. Block blk owns batch rows 2*blk and 2*blk+1.
// ---------------------------------------------------------------------------
__device__ void dev_phaseA(int blk, int tid, const int* __restrict__ asp,
                           const float* __restrict__ emb,
                           const float* __restrict__ Wx,
                           const float* __restrict__ bx,
                           float* __restrict__ ws, int use16, CoopU* u)
{
    const int wv = tid >> 6, lane = tid & 63;
    // X0 aspect means for both rows
    int r = -1, col = 0;
    if (tid < DD) { r = 0; col = tid; }
    else if (tid >= 512 && tid < 512 + DD) { r = 1; col = tid - 512; }
    if (r >= 0) {
        const int bb = 2 * blk + r;
        float na = 0.f, a = 0.f;
        #pragma unroll
        for (int k = 0; k < 8; ++k) {
            const int idx = asp[bb * 8 + k];
            na += (idx != 0) ? 1.0f : 0.0f;
            a += emb[(size_t)idx * DD + col];
        }
        ws[X0_OFF + bb * 304 + col] = a / na;
    }

    if (blk != 0) {
        // eu + e16 over vocab (blocks 1..255 grid-stride)
        if (tid < DD) u->t.u_s[tid] = ws[U_OFF + tid];
        __syncthreads();
        const float4* u4 = (const float4*)u->t.u_s;
        const float4  q0 = u4[lane];
        const float4  q1 = (lane < 11) ? u4[64 + lane] : float4{0, 0, 0, 0};
        ushort4* e16 = (ushort4*)(ws + E16_OFF);
        const int gw     = (blk - 1) * 16 + wv;
        const int stride = 255 * 16;
        for (int v = gw; v < VV; v += stride) {
            const float4* er = (const float4*)(emb + (size_t)v * DD);
            const float4 e0 = er[lane];
            float4 e1{0, 0, 0, 0};
            float a = e0.x * q0.x + e0.y * q0.y + e0.z * q0.z + e0.w * q0.w;
            if (lane < 11) {
                e1 = er[64 + lane];
                a += e1.x * q1.x + e1.y * q1.y + e1.z * q1.z + e1.w * q1.w;
            }
            #pragma unroll
            for (int off = 32; off; off >>= 1) a += __shfl_xor(a, off);
            if (lane == 0) ws[EU_OFF + v] = a;
            if (use16) {
                ushort4 h0;
                h0.x = __half_as_ushort(__float2half(e0.x));
                h0.y = __half_as_ushort(__float2half(e0.y));
                h0.z = __half_as_ushort(__float2half(e0.z));
                h0.w = __half_as_ushort(__float2half(e0.w));
                e16[(size_t)v * NF4 + lane] = h0;
                if (lane < 11) {
                    ushort4 h1;
                    h1.x = __half_as_ushort(__float2half(e1.x));
                    h1.y = __half_as_ushort(__float2half(e1.y));
                    h1.z = __half_as_ushort(__float2half(e1.z));
                    h1.w = __half_as_ushort(__float2half(e1.w));
                    e16[(size_t)v * NF4 + 64 + lane] = h1;
                }
            }
        }
    } else {
        // block 0: uqWx = Wx^T @ uq ; c_qs = c_q + dot(uq, bx)
        if (tid < DD) u->p.uq_s[tid] = ws[UQ_OFF + tid];
        __syncthreads();
        {
            const int g = tid / 304;
            const int j = tid - g * 304;
            if (g < 3 && j < DD) {
                const int e0 = g * 100;
                float a = 0.f;
                for (int i2 = e0; i2 < e0 + 100; ++i2)
                    a += u->p.uq_s[i2] * Wx[i2 * DD + j];
                u->p.p0[g][j] = a;
            }
        }
        float pq = (tid < DD) ? u->p.uq_s[tid] * bx[tid] : 0.f;
        #pragma unroll
        for (int off = 32; off; off >>= 1) pq += __shfl_xor(pq, off);
        if (lane == 0) u->p.red0[wv] = pq;
        __syncthreads();
        if (tid < DD)
            ws[UQWX_OFF + tid] = u->p.p0[0][tid] + u->p.p0[1][tid] + u->p.p0[2][tid];
        if (tid == 0) {
            float s = 0.f;
            for (int w = 0; w < 16; ++w) s += u->p.red0[w];
            ws[CQS] = ws[CQ] + s;
        }
    }
}

__device__ __forceinline__ void gemm2(const float* __restrict__ W,
                                      const float (*As)[304],
                                      float (*part)[2][304], int tid)
{
    const int g = tid / 304;
    const int i = tid - g * 304;
    if (g < 3 && i < DD) {
        const int e0 = g * 100;
        float a0 = 0.f, a1 = 0.f;
        for (int e = e0; e < e0 + 100; e += 2) {
            const float w0 = W[e * DD + i];
            const float w1 = W[(e + 1) * DD + i];
            a0 += As[0][e] * w0 + As[0][e + 1] * w1;
            a1 += As[1][e] * w0 + As[1][e + 1] * w1;
        }
        part[g][0][i] = a0;
        part[g][1][i] = a1;
    }
}

__device__ void dev_qs2(int b0, int tid, const float* __restrict__ ws_c,
                        float* __restrict__ ws, const float (*As)[304])
{
    const int wv = tid >> 6, lane = tid & 63;
    if (wv < 2) {
        const float4* x4 = (const float4*)As[wv];
        const float4* q4 = (const float4*)(ws_c + UQWX_OFF);
        const float4 xa = x4[lane], ua = q4[lane];
        float a = xa.x * ua.x + xa.y * ua.y + xa.z * ua.z + xa.w * ua.w;
        if (lane < 11) {
            const float4 xb = x4[64 + lane], ub = q4[64 + lane];
            a += xb.x * ub.x + xb.y * ub.y + xb.z * ub.z + xb.w * ub.w;
        }
        #pragma unroll
        for (int off = 32; off; off >>= 1) a += __shfl_xor(a, off);
        if (lane == 0) ws[QS_OFF + b0 + wv] = a + ws_c[CQS];
    }
}

__device__ void dev_phaseB(int blk, int tid, const int* __restrict__ text,
                           const float* __restrict__ bx,
                           float* __restrict__ ws, CoopU* u)
{
    const int wv = tid >> 6, lane = tid & 63;
    const int b0 = 2 * blk;
    const int rr = tid >> 9;          // 0/1: which row this thread serves
    const int s  = tid & 511;
    const int bb = b0 + rr;

    const int t = text[bb * SS + s];
    const unsigned long long bal = __ballot(t != 0);
    if (lane == 0) u->c.red[wv] = (float)__popcll(bal);
    __syncthreads();

    int len = 0;
    {
        const int w0 = rr * 8;
        #pragma unroll
        for (int w = 0; w < 8; ++w) len += (int)u->c.red[w0 + w];
    }
    const int   s0   = SS - len;
    const float lenf = (float)len;
    {
        const int j = s - s0;
        const float wg = (j >= 0) ? (1.0f - (float)j / lenf) : 1.0f;
        ws[KS_OFF + bb * SS + s] = wg * ws[EU_OFF + t] + ws[CK];
    }
    if (s == 0) ((int*)(ws + S0_OFF))[bb] = s0;
    __syncthreads();

    // gemm0: XN = X0 @ WxT + bx ; qs
    for (int idx = tid; idx < 2 * DD; idx += 1024) {
        const int b2 = idx / DD, e = idx - b2 * DD;
        u->g.As[b2][e] = ws[X0_OFF + (b0 + b2) * 304 + e];
    }
    __syncthreads();
    gemm2(ws + WXT_OFF, u->g.As, u->g.part, tid);
    __syncthreads();
    for (int idx = tid; idx < 2 * DD; idx += 1024) {
        const int b2 = idx / DD, e = idx - b2 * DD;
        ws[XN_OFF + (b0 + b2) * 304 + e] =
            u->g.part[0][b2][e] + u->g.part[1][b2][e] + u->g.part[2][b2][e] + bx[e];
    }
    dev_qs2(b0, tid, ws, ws, u->g.As);
}

__device__ void dev_attn(int blk, int tid, const int* __restrict__ text,
                         const float* __restrict__ emb,
                         float* __restrict__ ws, int use16, CoopU* u)
{
    const int wv = tid >> 6, lane = tid & 63;
    const float c_k = ws[CK];

    for (int r = 0; r < 2; ++r) {
        if (r) __syncthreads();
        const int bb  = 2 * blk + r;
        const int s0  = ((const int*)(ws + S0_OFF))[bb];
        const float lenf = (float)(SS - s0);
        const float qs = ws[QS_OFF + bb];

        float p = 0.f;
        if (tid < SS) {
            const int t = text[bb * SS + tid];
            u->a.ti[tid] = t;
            if (tid >= s0) {
                p = fast_exp_tanh(ws[KS_OFF + bb * SS + tid] + qs);
                u->a.cw[tid] = p * (1.0f - (float)(tid - s0) / lenf);
            }
        }
        float sp = p;
        #pragma unroll
        for (int off = 32; off; off >>= 1) sp += __shfl_xor(sp, off);
        if (lane == 0 && wv < 8) u->a.red[wv] = sp;
        __syncthreads();

        float4 acc{0, 0, 0, 0}, accb{0, 0, 0, 0};
        const int start = s0 + ((wv - s0) & 15);
        if (use16) {
            const ushort4* e16 = (const ushort4*)(ws + E16_OFF);
            const int cnt = (SS - start + 15) >> 4;
            ushort4 ca[4] = {}, cb[4] = {};
            #pragma unroll
            for (int k = 0; k < 4; ++k) {
                if (k < cnt) {
                    const ushort4* rp = e16 + (size_t)u->a.ti[start + k * 16] * NF4;
                    ca[k] = rp[lane];
                    if (lane < 11) cb[k] = rp[64 + lane];
                }
            }
            for (int base = 0; base < cnt; base += 4) {
                ushort4 na[4] = {}, nb[4] = {};
                #pragma unroll
                for (int k = 0; k < 4; ++k) {
                    const int rn = base + 4 + k;
                    if (rn < cnt) {
                        const ushort4* rp = e16 + (size_t)u->a.ti[start + rn * 16] * NF4;
                        na[k] = rp[lane];
                        if (lane < 11) nb[k] = rp[64 + lane];
                    }
                }
                #pragma unroll
                for (int k = 0; k < 4; ++k) {
                    const int rr2 = base + k;
                    if (rr2 < cnt) {
                        const float cc = u->a.cw[start + rr2 * 16];
                        const float2 f0 = __half22float2(*(const __half2*)&ca[k].x);
                        const float2 f1 = __half22float2(*(const __half2*)&ca[k].z);
                        acc.x += cc * f0.x; acc.y += cc * f0.y;
                        acc.z += cc * f1.x; acc.w += cc * f1.y;
                        if (lane < 11) {
                            const float2 g0 = __half22float2(*(const __half2*)&cb[k].x);
                            const float2 g1 = __half22float2(*(const __half2*)&cb[k].z);
                            accb.x += cc * g0.x; accb.y += cc * g0.y;
                            accb.z += cc * g1.x; accb.w += cc * g1.y;
                        }
                    }
                }
                #pragma unroll
                for (int k = 0; k < 4; ++k) { ca[k] = na[k]; cb[k] = nb[k]; }
            }
        } else {
            for (int s = start; s < SS; s += 16) {
                const float cc = u->a.cw[s];
                const float4* er = (const float4*)(emb + (size_t)u->a.ti[s] * DD);
                const float4 f = er[lane];
                acc.x += cc * f.x; acc.y += cc * f.y;
                acc.z += cc * f.z; acc.w += cc * f.w;
                if (lane < 11) {
                    const float4 f1 = er[64 + lane];
                    accb.x += cc * f1.x; accb.y += cc * f1.y;
                    accb.z += cc * f1.z; accb.w += cc * f1.w;
                }
            }
        }
        ((float4*)&u->a.mpart[wv][0])[lane] = acc;
        if (lane < 11) ((float4*)&u->a.mpart[wv][0])[64 + lane] = accb;
        __syncthreads();

        if (tid < DD) {
            float sumP = (float)s0 * fast_exp_tanh(c_k + qs);
            #pragma unroll
            for (int w = 0; w < 8; ++w) sumP += u->a.red[w];
            float mm = 0.f;
            #pragma unroll
            for (int w = 0; w < 16; ++w) mm += u->a.mpart[w][tid];
            ws[MV_OFF + bb * 304 + tid] = mm / sumP;
        }
    }
}

__device__ void dev_gemmH(int blk, int tid, int hop,
                          const float* __restrict__ Wd,
                          const float* __restrict__ bd,
                          const float* __restrict__ bx,
                          float* __restrict__ ws, float* __restrict__ out,
                          CoopU* u)
{
    const int wv = tid >> 6, lane = tid & 63;
    const int b0 = 2 * blk;

    for (int idx = tid; idx < 2 * DD; idx += 1024) {
        const int b2 = idx / DD, e = idx - b2 * DD;
        u->g.As[b2][e] = ws[MV_OFF + (b0 + b2) * 304 + e];
    }
    __syncthreads();
    gemm2(ws + WCT_OFF, u->g.As, u->g.part, tid);
    __syncthreads();
    for (int idx = tid; idx < 2 * DD; idx += 1024) {
        const int b2 = idx / DD, e = idx - b2 * DD;
        u->g.As[b2][e] = u->g.part[0][b2][e] + u->g.part[1][b2][e]
                       + u->g.part[2][b2][e] + ws[BC_OFF + e]
                       + ws[XN_OFF + (b0 + b2) * 304 + e];
    }
    __syncthreads();

    if (hop == 2) {
        if (wv < 6) {
            const int b2 = wv / 3, pp = wv - b2 * 3;
            const float4* wr = (const float4*)(Wd + pp * DD);
            const float4* x4 = (const float4*)u->g.As[b2];
            const float4 w0 = wr[lane], v0 = x4[lane];
            float a = w0.x * v0.x + w0.y * v0.y + w0.z * v0.z + w0.w * v0.w;
            if (lane < 11) {
                const float4 w1 = wr[64 + lane], v1 = x4[64 + lane];
                a += w1.x * v1.x + w1.y * v1.y + w1.z * v1.z + w1.w * v1.w;
            }
            #pragma unroll
            for (int off = 32; off; off >>= 1) a += __shfl_xor(a, off);
            if (lane == 0) out[(b0 + b2) * 3 + pp] = a + bd[pp];
        }
        return;
    }

    gemm2(ws + WXT_OFF, u->g.As, u->g.part, tid);
    __syncthreads();
    for (int idx = tid; idx < 2 * DD; idx += 1024) {
        const int b2 = idx / DD, e = idx - b2 * DD;
        ws[XN_OFF + (b0 + b2) * 304 + e] =
            u->g.part[0][b2][e] + u->g.part[1][b2][e] + u->g.part[2][b2][e] + bx[e];
    }
    dev_qs2(b0, tid, ws, ws, u->g.As);
}

// ---------------------------------------------------------------------------
// Cooperative mega-kernel: 256 blocks x 1024 (1 block/CU guaranteed).
// ---------------------------------------------------------------------------
__global__ __launch_bounds__(1024, 4) void coop_main(
    const int* __restrict__ text, const int* __restrict__ asp,
    const float* __restrict__ emb, const float* __restrict__ Wx,
    const float* __restrict__ Wd, const float* __restrict__ bd,
    const float* __restrict__ bx,
    float* __restrict__ ws, float* __restrict__ out, const int use16)
{
    cg::grid_group grid = cg::this_grid();
    const int blk = blockIdx.x;
    const int tid = threadIdx.x;
    __shared__ CoopU u;

    dev_phaseA(blk, tid, asp, emb, Wx, bx, ws, use16, &u);
    grid.sync();
    dev_phaseB(blk, tid, text, bx, ws, &u);
    grid.sync();
    for (int hop = 0; hop < 3; ++hop) {
        dev_attn(blk, tid, text, emb, ws, use16, &u);
        grid.sync();
        dev_gemmH(blk, tid, hop, Wd, bd, bx, ws, out, &u);
        if (hop < 2) grid.sync();
    }
}

// ---------------------------------------------------------------------------
// Fallback wrappers (used if cooperative launch is rejected).
// ---------------------------------------------------------------------------
__global__ __launch_bounds__(1024, 4) void k_phaseA(
    const int* __restrict__ asp, const float* __restrict__ emb,
    const float* __restrict__ Wx, const float* __restrict__ bx,
    float* __restrict__ ws, const int use16)
{
    __shared__ CoopU u;
    dev_phaseA(blockIdx.x, threadIdx.x, asp, emb, Wx, bx, ws, use16, &u);
}

__global__ __launch_bounds__(1024, 4) void k_phaseB(
    const int* __restrict__ text, const float* __restrict__ bx,
    float* __restrict__ ws)
{
    __shared__ CoopU u;
    dev_phaseB(blockIdx.x, threadIdx.x, text, bx, ws, &u);
}

__global__ __launch_bounds__(1024, 4) void k_attn(
    const int* __restrict__ text, const float* __restrict__ emb,
    float* __restrict__ ws, const int use16)
{
    __shared__ CoopU u;
    dev_attn(blockIdx.x, threadIdx.x, text, emb, ws, use16, &u);
}

__global__ __launch_bounds__(1024, 4) void k_gemmH(
    const float* __restrict__ Wd, const float* __restrict__ bd,
    const float* __restrict__ bx, float* __restrict__ ws,
    float* __restrict__ out, const int hop)
{
    __shared__ CoopU u;
    dev_gemmH(blockIdx.x, threadIdx.x, hop, Wd, bd, bx, ws, out, &u);
}

extern "C" void kernel_launch(void* const* d_in, const int* in_sizes, int n_in,
                              void* d_out, int out_size, void* d_ws, size_t ws_size,
                              hipStream_t stream)
{
    const int*   text = (const int*)d_in[0];
    const int*   asp  = (const int*)d_in[1];
    const float* emb  = (const float*)d_in[2];
    const float* Wx   = (const float*)d_in[3];
    const float* bx   = (const float*)d_in[4];
    const float* Wk   = (const float*)d_in[5];
    const float* bk   = (const float*)d_in[6];
    const float* Wq   = (const float*)d_in[7];
    const float* bq   = (const float*)d_in[8];
    const float* wm   = (const float*)d_in[9];
    const float* Wp   = (const float*)d_in[10];
    const float* bp   = (const float*)d_in[11];
    const float* Wd   = (const float*)d_in[12];
    const float* bd   = (const float*)d_in[13];
    float* out = (float*)d_out;
    float* ws  = (float*)d_ws;

    const size_t need = (size_t)E16_OFF * 4 + (size_t)VV * DD * 2;
    int use16 = (ws_size >= need) ? 1 : 0;

    pre<<<202, 1024, 0, stream>>>(Wk, bk, Wq, bq, wm, Wp, bp, Wx, ws);

    void* args[] = {
        (void*)&text, (void*)&asp, (void*)&emb, (void*)&Wx,
        (void*)&Wd, (void*)&bd, (void*)&bx,
        (void*)&ws, (void*)&out, (void*)&use16
    };
    hipError_t err = hipLaunchCooperativeKernel((const void*)coop_main,
                                                dim3(256), dim3(1024),
                                                args, 0, stream);
    if (err != hipSuccess) {
        (void)hipGetLastError();   // clear sticky error; fall back
        k_phaseA<<<256, 1024, 0, stream>>>(asp, emb, Wx, bx, ws, use16);
        k_phaseB<<<256, 1024, 0, stream>>>(text, bx, ws);
        for (int hop = 0; hop < 3; ++hop) {
            k_attn<<<256, 1024, 0, stream>>>(text, emb, ws, use16);
            k_gemmH<<<256, 1024, 0, stream>>>(Wd, bd, bx, ws, out, hop);
        }
    }
}

// Round 10
// 267.469 us; speedup vs baseline: 2.0631x; 2.0631x over previous
//
#include <hip/hip_runtime.h>
#include <hip/hip_fp16.h>

#define DD 300
#define SS 512
#define VV 50000
#define NF4 75
#define NCH 8          // chunks per batch row in k_attn

// Workspace layout (float index):
#define CK       0
#define CQ       1
#define CQS      2
#define U_OFF    16       // u  = wk@Wk (300)
#define UQ_OFF   320      // uq = wq@Wq (300)
#define UQWX_OFF 640      // uqWx = Wx^T@uq (300)
#define BC_OFF   960      // bc = Wp@bk+bp (300)
#define WXT_OFF  2048     // WxT[e*300+i] = Wx[i,e] (90000)
#define WCT_OFF  92160    // WcT[e*300+i] = (Wp@Wk)[i,e] (90000)
#define QS_OFF   182272   // qs[b] (512)
#define S0_OFF   182784   // s0[b] (512 ints)
#define M_OFF    183296   // M[b*304+j] atomic accumulator (512*304)
#define XN_OFF   338944   // XN[b*300+i] (153600)
#define KS_OFF   492544   // ks[b*512+s] (262144)
#define SP_OFF   754688   // sumP[b] atomic accumulator (512)
#define EU_OFF   755200   // eu[v] (50000)
#define E16_OFF  805376   // fp16 emb copy (600 B/row)

#define FMA4(acc, s, v) { acc.x += (s)*(v).x; acc.y += (s)*(v).y; \
                          acc.z += (s)*(v).z; acc.w += (s)*(v).w; }

__device__ __forceinline__ float fast_exp_tanh(float z) {
    const float t = __expf(2.0f * z);
    return __expf(1.0f - 2.0f / (t + 1.0f));
}

// ---------------------------------------------------------------------------
// pre: 203 blocks x 1024.
//   0..99  : WcT rows (transposed store)
//   100..199: Wx->WxT transpose tiles
//   200    : u = wk@Wk, c_k
//   201    : uq = wq@Wq, c_q, bc = Wp@bk+bp
//   202    : uq (recomputed locally) -> uqWx = uq@Wx, c_qs = dot(bq,wq)+dot(uq,bx)
// ---------------------------------------------------------------------------
__global__ __launch_bounds__(1024) void pre(
    const float* __restrict__ Wk, const float* __restrict__ bk,
    const float* __restrict__ Wq, const float* __restrict__ bq,
    const float* __restrict__ w_mlp,
    const float* __restrict__ Wp, const float* __restrict__ bp,
    const float* __restrict__ Wx, const float* __restrict__ bx,
    float* __restrict__ ws)
{
    const int blk  = blockIdx.x;
    const int tid  = threadIdx.x;
    const int wv   = tid >> 6;
    const int lane = tid & 63;
    __shared__ __align__(16) float buf[16 * 304 * 3 + 3 * 304];
    __shared__ float red[16];

    if (blk < 100) {
        const int i0 = blk * 3;
        float* sWp = buf + 16 * 304 * 3;
        for (int r = tid; r < 3 * DD; r += 1024)
            sWp[(r / DD) * 304 + (r % DD)] = Wp[i0 * DD + r];
        __syncthreads();

        float4 a00{0,0,0,0}, a01{0,0,0,0}, a10{0,0,0,0},
               a11{0,0,0,0}, a20{0,0,0,0}, a21{0,0,0,0};
        for (int e = wv; e < DD; e += 16) {
            const float4* kr = (const float4*)(Wk + e * DD);
            const float4 k0 = kr[lane];
            const float p0 = sWp[e], p1 = sWp[304 + e], p2 = sWp[608 + e];
            FMA4(a00, p0, k0); FMA4(a10, p1, k0); FMA4(a20, p2, k0);
            if (lane < 11) {
                const float4 k1 = kr[64 + lane];
                FMA4(a01, p0, k1); FMA4(a11, p1, k1); FMA4(a21, p2, k1);
            }
        }
        float4* p0r = (float4*)(buf + (wv * 3 + 0) * 304);
        float4* p1r = (float4*)(buf + (wv * 3 + 1) * 304);
        float4* p2r = (float4*)(buf + (wv * 3 + 2) * 304);
        p0r[lane] = a00; p1r[lane] = a10; p2r[lane] = a20;
        if (lane < 11) { p0r[64+lane] = a01; p1r[64+lane] = a11; p2r[64+lane] = a21; }
        __syncthreads();
        if (tid < DD) {
            #pragma unroll
            for (int r = 0; r < 3; ++r) {
                float s = 0.f;
                for (int w = 0; w < 16; ++w) s += buf[(w * 3 + r) * 304 + tid];
                ws[WCT_OFF + tid * DD + i0 + r] = s;
            }
        }
        return;
    }

    if (blk < 200) {
        const int tb = blk - 100;
        const int bi = tb / 10, bj = tb % 10;
        __shared__ __align__(16) float tile[32][33];
        const int ty = tid >> 5, tx = tid & 31;
        {
            const int r = bi * 32 + ty, c = bj * 32 + tx;
            if (r < DD && c < DD) tile[ty][tx] = Wx[r * DD + c];
        }
        __syncthreads();
        {
            const int ro = bj * 32 + ty, co = bi * 32 + tx;
            if (ro < DD && co < DD) ws[WXT_OFF + ro * DD + co] = tile[tx][ty];
        }
        return;
    }

    if (blk < 202) {
        const float* M  = (blk == 200) ? Wk : Wq;
        const float* vw = (blk == 200) ? w_mlp : (w_mlp + DD);
        float* s_w = buf + 16 * 304;
        float* s_b = buf + 16 * 304 + 304;
        if (tid < DD) {
            s_w[tid] = vw[tid];
            if (blk == 201) s_b[tid] = bk[tid];
        }
        __syncthreads();

        float4 a0{0,0,0,0}, a1{0,0,0,0};
        for (int e = wv; e < DD; e += 16) {
            const float4* kr = (const float4*)(M + e * DD);
            const float s = s_w[e];
            FMA4(a0, s, kr[lane]);
            if (lane < 11) { const float4 k1 = kr[64 + lane]; FMA4(a1, s, k1); }
        }
        float4* pr = (float4*)(buf + wv * 304);
        pr[lane] = a0;
        if (lane < 11) pr[64 + lane] = a1;

        float pk = 0.f;
        if (tid < DD) pk = ((blk == 200) ? bk[tid] : bq[tid]) * s_w[tid];
        #pragma unroll
        for (int off = 32; off; off >>= 1) pk += __shfl_xor(pk, off);
        if (lane == 0) red[wv] = pk;
        __syncthreads();

        const int voff = (blk == 200) ? U_OFF : UQ_OFF;
        if (tid < DD) {
            float s = 0.f;
            #pragma unroll
            for (int w = 0; w < 16; ++w) s += buf[w * 304 + tid];
            ws[voff + tid] = s;
        }
        if (tid == 0) {
            float s = 0.f;
            for (int w = 0; w < 16; ++w) s += red[w];
            ws[(blk == 200) ? CK : CQ] = s;
        }
        if (blk == 201) {
            const float4* b4 = (const float4*)s_b;
            const float4 k0 = b4[lane];
            const float4 k1 = (lane < 11) ? b4[64 + lane] : float4{0, 0, 0, 0};
            for (int i2 = wv; i2 < DD; i2 += 16) {
                const float4* wr = (const float4*)(Wp + i2 * DD);
                const float4 w0 = wr[lane];
                float a = w0.x * k0.x + w0.y * k0.y + w0.z * k0.z + w0.w * k0.w;
                if (lane < 11) {
                    const float4 w1 = wr[64 + lane];
                    a += w1.x * k1.x + w1.y * k1.y + w1.z * k1.z + w1.w * k1.w;
                }
                #pragma unroll
                for (int off = 32; off; off >>= 1) a += __shfl_xor(a, off);
                if (lane == 0) ws[BC_OFF + i2] = a + bp[i2];
            }
        }
        return;
    }

    // blk 202: recompute uq locally, then uqWx = uq@Wx, c_qs.
    {
        float* s_w = buf + 16 * 304;        // wq
        float* s_u = buf + 16 * 304 + 304;  // uq (full)
        if (tid < DD) s_w[tid] = w_mlp[DD + tid];
        __syncthreads();

        // pass 1: uq = sum_e wq[e] * Wq[e,:]
        float4 a0{0,0,0,0}, a1{0,0,0,0};
        for (int e = wv; e < DD; e += 16) {
            const float4* kr = (const float4*)(Wq + e * DD);
            const float s = s_w[e];
            FMA4(a0, s, kr[lane]);
            if (lane < 11) { const float4 k1 = kr[64 + lane]; FMA4(a1, s, k1); }
        }
        float4* pr = (float4*)(buf + wv * 304);
        pr[lane] = a0;
        if (lane < 11) pr[64 + lane] = a1;
        __syncthreads();
        if (tid < DD) {
            float s = 0.f;
            #pragma unroll
            for (int w = 0; w < 16; ++w) s += buf[w * 304 + tid];
            s_u[tid] = s;
        }
        __syncthreads();

        // pass 2: uqWx = sum_i uq[i] * Wx[i,:]
        float4 b0{0,0,0,0}, b1{0,0,0,0};
        for (int i2 = wv; i2 < DD; i2 += 16) {
            const float4* xr = (const float4*)(Wx + i2 * DD);
            const float s = s_u[i2];
            FMA4(b0, s, xr[lane]);
            if (lane < 11) { const float4 x1 = xr[64 + lane]; FMA4(b1, s, x1); }
        }
        // c_q + dot(uq, bx) partials
        float pk = 0.f;
        if (tid < DD) pk = bq[tid] * s_w[tid] + s_u[tid] * bx[tid];
        #pragma unroll
        for (int off = 32; off; off >>= 1) pk += __shfl_xor(pk, off);
        if (lane == 0) red[wv] = pk;
        __syncthreads();
        float4* qr = (float4*)(buf + wv * 304);
        qr[lane] = b0;
        if (lane < 11) qr[64 + lane] = b1;
        __syncthreads();
        if (tid < DD) {
            float s = 0.f;
            #pragma unroll
            for (int w = 0; w < 16; ++w) s += buf[w * 304 + tid];
            ws[UQWX_OFF + tid] = s;
        }
        if (tid == 0) {
            float s = 0.f;
            for (int w = 0; w < 16; ++w) s += red[w];
            ws[CQS] = s;
        }
    }
}

// ---------------------------------------------------------------------------
// tables: eu[v] = dot(emb[v], u) + fp16 emb copy. 512 x 1024.
// ---------------------------------------------------------------------------
__global__ __launch_bounds__(1024) void build_tables(
    const float* __restrict__ emb, float* __restrict__ ws, const int do16)
{
    const int tid  = threadIdx.x;
    const int wv   = tid >> 6;
    const int lane = tid & 63;
    __shared__ __align__(16) float u_s[DD];
    if (tid < DD) u_s[tid] = ws[U_OFF + tid];
    __syncthreads();

    const float4* u4 = (const float4*)u_s;
    const float4  q0 = u4[lane];
    const float4  q1 = (lane < 11) ? u4[64 + lane] : float4{0, 0, 0, 0};
    ushort4* e16 = (ushort4*)(ws + E16_OFF);

    const int gw     = blockIdx.x * 16 + wv;
    const int stride = gridDim.x * 16;
    for (int v = gw; v < VV; v += stride) {
        const float4* er = (const float4*)(emb + (size_t)v * DD);
        const float4 e0 = er[lane];
        float4 e1{0, 0, 0, 0};
        float a = e0.x * q0.x + e0.y * q0.y + e0.z * q0.z + e0.w * q0.w;
        if (lane < 11) {
            e1 = er[64 + lane];
            a += e1.x * q1.x + e1.y * q1.y + e1.z * q1.z + e1.w * q1.w;
        }
        #pragma unroll
        for (int off = 32; off; off >>= 1) a += __shfl_xor(a, off);
        if (lane == 0) ws[EU_OFF + v] = a;
        if (do16) {
            ushort4 h0;
            h0.x = __half_as_ushort(__float2half(e0.x));
            h0.y = __half_as_ushort(__float2half(e0.y));
            h0.z = __half_as_ushort(__float2half(e0.z));
            h0.w = __half_as_ushort(__float2half(e0.w));
            e16[(size_t)v * NF4 + lane] = h0;
            if (lane < 11) {
                ushort4 h1;
                h1.x = __half_as_ushort(__float2half(e1.x));
                h1.y = __half_as_ushort(__float2half(e1.y));
                h1.z = __half_as_ushort(__float2half(e1.z));
                h1.w = __half_as_ushort(__float2half(e1.w));
                e16[(size_t)v * NF4 + 64 + lane] = h1;
            }
        }
    }
}

// ---------------------------------------------------------------------------
// k_init0: per b (512 blocks x 512 threads): s0, ks row, aspect-mean X0
// (LDS only), XN = X0@WxT + bx, qs; zero M/SP for hop-0 attn.
// ---------------------------------------------------------------------------
__global__ __launch_bounds__(512) void k_init0(
    const int* __restrict__ text, const int* __restrict__ asp,
    const float* __restrict__ emb, const float* __restrict__ bx,
    float* __restrict__ ws)
{
    const int b    = blockIdx.x;
    const int tid  = threadIdx.x;
    const int wv   = tid >> 6;
    const int lane = tid & 63;
    __shared__ float red[8];
    __shared__ float red2[8];
    __shared__ __align__(16) float sx[304];

    const int t = text[b * SS + tid];
    const unsigned long long bal = __ballot(t != 0);
    if (lane == 0) red[wv] = (float)__popcll(bal);

    if (tid < DD) {
        float na = 0.f, a = 0.f;
        #pragma unroll
        for (int k = 0; k < 8; ++k) {
            const int idx = asp[b * 8 + k];
            na += (idx != 0) ? 1.0f : 0.0f;
            a += emb[(size_t)idx * DD + tid];
        }
        sx[tid] = a / na;
    }
    __syncthreads();

    int len = 0;
    #pragma unroll
    for (int w = 0; w < 8; ++w) len += (int)red[w];
    const int   s0   = SS - len;
    const float lenf = (float)len;
    {
        const int j = tid - s0;
        const float wg = (j >= 0) ? (1.0f - (float)j / lenf) : 1.0f;
        ws[KS_OFF + b * SS + tid] = wg * ws[EU_OFF + t] + ws[CK];
    }
    if (tid == 0) {
        ((int*)(ws + S0_OFF))[b] = s0;
        ws[SP_OFF + b] = 0.f;
    }
    if (tid < 304) ws[M_OFF + b * 304 + tid] = 0.f;

    // XN = X0 @ WxT + bx (thread-per-output-column, coalesced)
    if (tid < DD) {
        const float* W = ws + WXT_OFF + tid;
        float a0 = 0.f, a1 = 0.f, a2 = 0.f, a3 = 0.f;
        for (int e = 0; e < DD; e += 4) {
            a0 += sx[e]     * W[(e)     * DD];
            a1 += sx[e + 1] * W[(e + 1) * DD];
            a2 += sx[e + 2] * W[(e + 2) * DD];
            a3 += sx[e + 3] * W[(e + 3) * DD];
        }
        ws[XN_OFF + b * DD + tid] = (a0 + a1) + (a2 + a3) + bx[tid];
    }

    // qs = dot(X0, uqWx) + c_qs
    float p = (tid < DD) ? sx[tid] * ws[UQWX_OFF + tid] : 0.f;
    #pragma unroll
    for (int off = 32; off; off >>= 1) p += __shfl_xor(p, off);
    if (lane == 0) red2[wv] = p;
    __syncthreads();
    if (tid == 0) {
        float s = 0.f;
        #pragma unroll
        for (int w = 0; w < 8; ++w) s += red2[w];
        ws[QS_OFF + b] = s + ws[CQS];
    }
}

// ---------------------------------------------------------------------------
// k_attn: 4096 blocks (b x 8 chunks) x 256 threads. Softmax coeffs hoisted;
// 4-deep prefetched fp16 row gathers; fp32 atomics into M[b], SP[b].
// (R7-validated.)
// ---------------------------------------------------------------------------
__global__ __launch_bounds__(256) void k_attn(
    const int* __restrict__ text, const float* __restrict__ emb,
    float* __restrict__ ws, const int use16)
{
    const int blk  = blockIdx.x;
    const int b    = blk >> 3;
    const int c    = blk & 7;
    const int tid  = threadIdx.x;
    const int wv   = tid >> 6;
    const int lane = tid & 63;

    const int s0  = ((const int*)(ws + S0_OFF))[b];
    const int len = SS - s0;
    const int q   = (len + NCH - 1) >> 3;
    const int sb  = s0 + c * q;
    if (sb >= SS) return;
    const int se = min(sb + q, SS);
    const int n  = se - sb;

    __shared__ int   stok[64];
    __shared__ float scw[64];
    __shared__ float sps[64];
    __shared__ __align__(16) float mpart[4][304];

    const float qs   = ws[QS_OFF + b];
    const float lenf = (float)len;
    if (tid < n) {
        const int s = sb + tid;
        stok[tid] = text[b * SS + s];
        const float p = fast_exp_tanh(ws[KS_OFF + b * SS + s] + qs);
        sps[tid] = p;
        scw[tid] = p * (1.0f - (float)(s - s0) / lenf);
    }
    __syncthreads();

    if (wv == 0) {
        float v = (lane < n) ? sps[lane] : 0.f;
        #pragma unroll
        for (int off = 32; off; off >>= 1) v += __shfl_xor(v, off);
        if (lane == 0) atomicAdd(ws + SP_OFF + b, v);
    }

    const int qw = (q + 3) >> 2;
    const int r0 = wv * qw;
    const int r1 = min(r0 + qw, n);

    float4 acc{0, 0, 0, 0}, accb{0, 0, 0, 0};

    if (use16) {
        const ushort4* e16 = (const ushort4*)(ws + E16_OFF);
        ushort4 ca[4] = {}, cb[4] = {};
        #pragma unroll
        for (int k = 0; k < 4; ++k) {
            const int r = r0 + k;
            if (r < r1) {
                const ushort4* rp = e16 + (size_t)stok[r] * NF4;
                ca[k] = rp[lane];
                if (lane < 11) cb[k] = rp[64 + lane];
            }
        }
        for (int base = r0; base < r1; base += 4) {
            ushort4 na[4] = {}, nb[4] = {};
            #pragma unroll
            for (int k = 0; k < 4; ++k) {
                const int rn = base + 4 + k;
                if (rn < r1) {
                    const ushort4* rp = e16 + (size_t)stok[rn] * NF4;
                    na[k] = rp[lane];
                    if (lane < 11) nb[k] = rp[64 + lane];
                }
            }
            #pragma unroll
            for (int k = 0; k < 4; ++k) {
                const int r = base + k;
                if (r < r1) {
                    const float cc = scw[r];
                    const float2 f0 = __half22float2(*(const __half2*)&ca[k].x);
                    const float2 f1 = __half22float2(*(const __half2*)&ca[k].z);
                    acc.x += cc * f0.x; acc.y += cc * f0.y;
                    acc.z += cc * f1.x; acc.w += cc * f1.y;
                    if (lane < 11) {
                        const float2 g0 = __half22float2(*(const __half2*)&cb[k].x);
                        const float2 g1 = __half22float2(*(const __half2*)&cb[k].z);
                        accb.x += cc * g0.x; accb.y += cc * g0.y;
                        accb.z += cc * g1.x; accb.w += cc * g1.y;
                    }
                }
            }
            #pragma unroll
            for (int k = 0; k < 4; ++k) { ca[k] = na[k]; cb[k] = nb[k]; }
        }
    } else {
        for (int r = r0; r < r1; ++r) {
            const float cc = scw[r];
            const float4* er = (const float4*)(emb + (size_t)stok[r] * DD);
            const float4 f = er[lane];
            acc.x += cc * f.x; acc.y += cc * f.y;
            acc.z += cc * f.z; acc.w += cc * f.w;
            if (lane < 11) {
                const float4 f1 = er[64 + lane];
                accb.x += cc * f1.x; accb.y += cc * f1.y;
                accb.z += cc * f1.z; accb.w += cc * f1.w;
            }
        }
    }
    ((float4*)&mpart[wv][0])[lane] = acc;
    if (lane < 11) ((float4*)&mpart[wv][0])[64 + lane] = accb;
    __syncthreads();

    for (int j = tid; j < DD; j += 256) {
        const float v = mpart[0][j] + mpart[1][j] + mpart[2][j] + mpart[3][j];
        atomicAdd(ws + M_OFF + b * 304 + j, v);
    }
}

// ---------------------------------------------------------------------------
// k_gemm: 256 blocks x 1024 threads, 2 batch rows per block.
// last==0: X = (M/sumP)@WcT+bc+XN; XN = X@WxT+bx; qs; zero M/SP.
// last==1: X = (M/sumP)@WcT+bc+XN; out = X@Wd^T+bd.
// ---------------------------------------------------------------------------
__global__ __launch_bounds__(1024) void k_gemm(
    float* __restrict__ ws, const float* __restrict__ bx,
    const float* __restrict__ Wd, const float* __restrict__ bd,
    float* __restrict__ out, const int last)
{
    const int b0   = blockIdx.x * 2;
    const int tid  = threadIdx.x;
    const int wv   = tid >> 6;
    const int lane = tid & 63;
    __shared__ __align__(16) float As[2][304];
    __shared__ __align__(16) float part[3][2][304];
    __shared__ float isp[2];

    if (tid < 2) {
        const int b = b0 + tid;
        const int s0 = ((const int*)(ws + S0_OFF))[b];
        const float qs = ws[QS_OFF + b];
        float sp = ws[SP_OFF + b];
        if (s0 > 0) sp += (float)s0 * fast_exp_tanh(ws[CK] + qs);
        isp[tid] = 1.0f / sp;
    }
    __syncthreads();
    for (int idx = tid; idx < 2 * DD; idx += 1024) {
        const int bb = idx / DD, e = idx - bb * DD;
        As[bb][e] = ws[M_OFF + (b0 + bb) * 304 + e] * isp[bb];
    }
    if (!last) {
        for (int idx = tid; idx < 2 * 304; idx += 1024) {
            const int bb = idx / 304, e = idx - bb * 304;
            ws[M_OFF + (b0 + bb) * 304 + e] = 0.f;
        }
        if (tid < 2) ws[SP_OFF + b0 + tid] = 0.f;
    }
    __syncthreads();

    const int g = tid / 304;
    const int i = tid - g * 304;
    const bool act = (g < 3) && (i < DD);

    // GEMM1: X = As @ WcT + bc + XN -> As
    if (act) {
        const float* W = ws + WCT_OFF;
        const int e0 = g * 100;
        float a0 = 0.f, a1 = 0.f;
        for (int e = e0; e < e0 + 100; e += 2) {
            const float w0 = W[e * DD + i];
            const float w1 = W[(e + 1) * DD + i];
            a0 += As[0][e] * w0 + As[0][e + 1] * w1;
            a1 += As[1][e] * w0 + As[1][e + 1] * w1;
        }
        part[g][0][i] = a0; part[g][1][i] = a1;
    }
    __syncthreads();
    for (int idx = tid; idx < 2 * DD; idx += 1024) {
        const int bb = idx / DD, e = idx - bb * DD;
        As[bb][e] = part[0][bb][e] + part[1][bb][e] + part[2][bb][e]
                  + ws[BC_OFF + e] + ws[XN_OFF + (b0 + bb) * DD + e];
    }
    __syncthreads();

    if (last) {
        if (wv < 6) {
            const int bb = wv / 3, p = wv - bb * 3;
            const float4* wr = (const float4*)(Wd + p * DD);
            const float4* x4 = (const float4*)As[bb];
            const float4 w0 = wr[lane], v0 = x4[lane];
            float a = w0.x * v0.x + w0.y * v0.y + w0.z * v0.z + w0.w * v0.w;
            if (lane < 11) {
                const float4 w1 = wr[64 + lane], v1 = x4[64 + lane];
                a += w1.x * v1.x + w1.y * v1.y + w1.z * v1.z + w1.w * v1.w;
            }
            #pragma unroll
            for (int off = 32; off; off >>= 1) a += __shfl_xor(a, off);
            if (lane == 0) out[(b0 + bb) * 3 + p] = a + bd[p];
        }
        return;
    }

    // GEMM2: XN = As @ WxT + bx
    if (act) {
        const float* W = ws + WXT_OFF;
        const int e0 = g * 100;
        float a0 = 0.f, a1 = 0.f;
        for (int e = e0; e < e0 + 100; e += 2) {
            const float w0 = W[e * DD + i];
            const float w1 = W[(e + 1) * DD + i];
            a0 += As[0][e] * w0 + As[0][e + 1] * w1;
            a1 += As[1][e] * w0 + As[1][e + 1] * w1;
        }
        part[g][0][i] = a0; part[g][1][i] = a1;
    }
    __syncthreads();
    for (int idx = tid; idx < 2 * DD; idx += 1024) {
        const int bb = idx / DD, e = idx - bb * DD;
        ws[XN_OFF + (b0 + bb) * DD + e] =
            part[0][bb][e] + part[1][bb][e] + part[2][bb][e] + bx[e];
    }
    // qs epilogue
    if (wv < 2) {
        const float4* x4 = (const float4*)As[wv];
        const float4* q4 = (const float4*)(ws + UQWX_OFF);
        const float4 xa = x4[lane], ua = q4[lane];
        float a = xa.x * ua.x + xa.y * ua.y + xa.z * ua.z + xa.w * ua.w;
        if (lane < 11) {
            const float4 xb = x4[64 + lane], ub = q4[64 + lane];
            a += xb.x * ub.x + xb.y * ub.y + xb.z * ub.z + xb.w * ub.w;
        }
        #pragma unroll
        for (int off = 32; off; off >>= 1) a += __shfl_xor(a, off);
        if (lane == 0) ws[QS_OFF + b0 + wv] = a + ws[CQS];
    }
}

extern "C" void kernel_launch(void* const* d_in, const int* in_sizes, int n_in,
                              void* d_out, int out_size, void* d_ws, size_t ws_size,
                              hipStream_t stream)
{
    const int*   text = (const int*)d_in[0];
    const int*   asp  = (const int*)d_in[1];
    const float* emb  = (const float*)d_in[2];
    const float* Wx   = (const float*)d_in[3];
    const float* bx   = (const float*)d_in[4];
    const float* Wk   = (const float*)d_in[5];
    const float* bk   = (const float*)d_in[6];
    const float* Wq   = (const float*)d_in[7];
    const float* bq   = (const float*)d_in[8];
    const float* wm   = (const float*)d_in[9];
    const float* Wp   = (const float*)d_in[10];
    const float* bp   = (const float*)d_in[11];
    const float* Wd   = (const float*)d_in[12];
    const float* bd   = (const float*)d_in[13];
    float* out = (float*)d_out;
    float* ws  = (float*)d_ws;

    const size_t need = (size_t)E16_OFF * 4 + (size_t)VV * DD * 2;
    const int use16 = (ws_size >= need) ? 1 : 0;

    pre<<<203, 1024, 0, stream>>>(Wk, bk, Wq, bq, wm, Wp, bp, Wx, bx, ws);
    build_tables<<<512, 1024, 0, stream>>>(emb, ws, use16);
    k_init0<<<512, 512, 0, stream>>>(text, asp, emb, bx, ws);
    for (int hop = 0; hop < 3; ++hop) {
        k_attn<<<512 * NCH, 256, 0, stream>>>(text, emb, ws, use16);
        k_gemm<<<256, 1024, 0, stream>>>(ws, bx, Wd, bd, out, (hop == 2) ? 1 : 0);
    }
}